// Round 1
// 256.007 us; speedup vs baseline: 1.3347x; 1.3347x over previous
//
#include <hip/hip_runtime.h>
#include <math.h>

// ---------------- problem constants (fixed by setup_inputs) ----------------
constexpr int N_  = 4096;      // nodes
constexpr int E_  = 131072;    // edges
constexpr int D_  = 512;       // EMBED
constexpr int FF_ = 1024;
constexpr int NG_ = 50;
constexpr int K_  = 32;        // fixed degree
constexpr float INV_SQRT2 = 0.70710678118654752440f;
constexpr float RBF_DELTA = 12.0f / 49.0f;                       // linspace(0,12,50) spacing
constexpr float RBF_COEFF = -0.5f * (49.0f/12.0f) * (49.0f/12.0f);

// ---------------- output layout (float32, concat in return order) ----------
constexpr long long TE_COLS  = 262144LL + 131072 + 131072 + 4194304 + 4194304; // 8912896
constexpr long long OFF_TOK   = 0;
constexpr long long OFF_EDGES = (long long)(N_ + E_) * D_;       // 69206016
constexpr long long OFF_VHAT  = OFF_EDGES + 2 * TE_COLS;         // 87031808
constexpr long long OFF_ADIST = OFF_VHAT + (long long)E_ * 3;    // 87425024
constexpr long long OFF_DIST  = OFF_ADIST + 262144;              // 87687168
constexpr long long OFF_CDD   = OFF_DIST + E_;                   // 87818240
constexpr long long OFF_CSS   = OFF_CDD + (long long)E_ * K_;    // 92012544
// edge-column segment starts
constexpr long long EC_ALL = 0;
constexpr long long EC_N2E = 262144;
constexpr long long EC_E2N = 393216;
constexpr long long EC_DND = 524288;
constexpr long long EC_SNS = 4718592;

typedef __attribute__((ext_vector_type(8))) short   short8;
typedef __attribute__((ext_vector_type(4))) short   s16x4;
typedef __attribute__((ext_vector_type(8))) __bf16  bf16x8;
typedef __attribute__((ext_vector_type(4))) float   f32x4;

static __device__ inline short f2bf(float x) {
    unsigned u = __float_as_uint(x);
    u = (u + 0x7FFFu + ((u >> 16) & 1u)) >> 16;
    return (short)u;
}
static __device__ inline f32x4 MFMA(short8 a, short8 b, f32x4 c) {
    return __builtin_amdgcn_mfma_f32_16x16x32_bf16(
        __builtin_bit_cast(bf16x8, a), __builtin_bit_cast(bf16x8, b), c, 0, 0, 0);
}

// ---------------- K1: node tokens ----------------
__global__ void k_node_tokens(const int* __restrict__ an, const float* __restrict__ emb,
                              const float* __restrict__ te, float* __restrict__ out)
{
    int idx = blockIdx.x * 256 + threadIdx.x;       // covers N_*128 float4 groups
    int n  = idx >> 7;
    int c  = (idx & 127) << 2;
    float4 e4 = *(const float4*)&emb[(size_t)an[n] * D_ + c];
    float4 t4 = *(const float4*)&te[c];             // type_embedding[0]
    float4 r;
    r.x = INV_SQRT2 * (e4.x + t4.x);
    r.y = INV_SQRT2 * (e4.y + t4.y);
    r.z = INV_SQRT2 * (e4.z + t4.z);
    r.w = INV_SQRT2 * (e4.w + t4.w);
    *(float4*)&out[OFF_TOK + (size_t)n * D_ + c] = r;
}

// ---------------- K2: edge geometry + n2e/e2n edge columns + rank scatter ---
__global__ void k_edge_geom(const float* __restrict__ pos, const int* __restrict__ ei,
                            float* __restrict__ out, int* __restrict__ cntD,
                            int* __restrict__ cntS, int* __restrict__ gD,
                            int* __restrict__ gS)
{
    int e = blockIdx.x * 256 + threadIdx.x;         // E_ threads
    int s = ei[e];
    int d = ei[E_ + e];
    float vx = pos[3*d+0] - pos[3*s+0];
    float vy = pos[3*d+1] - pos[3*s+1];
    float vz = pos[3*d+2] - pos[3*s+2];
    float dist = sqrtf(vx*vx + vy*vy + vz*vz);
    out[OFF_DIST + e] = dist;
    float inv = 1.0f / fmaxf(dist, 1e-12f);
    out[OFF_VHAT + (size_t)e*3 + 0] = vx * inv;
    out[OFF_VHAT + (size_t)e*3 + 1] = vy * inv;
    out[OFF_VHAT + (size_t)e*3 + 2] = vz * inv;
    out[OFF_EDGES + EC_N2E + e]           = (float)s;
    out[OFF_EDGES + TE_COLS + EC_N2E + e] = (float)(N_ + e);
    out[OFF_EDGES + EC_E2N + e]           = (float)(N_ + e);
    out[OFF_EDGES + TE_COLS + EC_E2N + e] = (float)d;
    // rank scatter (was K4)
    int rd = atomicAdd(&cntD[d], 1);
    gD[(size_t)d * K_ + rd] = e;
    int rs = atomicAdd(&cntS[s], 1);
    gS[(size_t)s * K_ + rs] = e;
}

// ---------------- K3: intra-graph all-pairs edges + all_dist ----------------
__global__ void k_all_pairs(const float* __restrict__ pos, float* __restrict__ out)
{
    int c = blockIdx.x * 256 + threadIdx.x;         // 262144 threads
    int b = c >> 12;
    int p = c & 4095;
    int i0 = b * 64 + (p & 63);
    int i1 = b * 64 + (p >> 6);
    out[OFF_EDGES + EC_ALL + c]           = (float)i0;
    out[OFF_EDGES + TE_COLS + EC_ALL + c] = (float)i1;
    float dx = pos[3*i1+0] - pos[3*i0+0];
    float dy = pos[3*i1+1] - pos[3*i0+1];
    float dz = pos[3*i1+2] - pos[3*i0+2];
    out[OFF_ADIST + c] = sqrtf(dx*dx + dy*dy + dz*dz);
}

// ---------------- K5: sort each 32-group ascending (bitonic, all-static idx) -
// rule #20: runtime-indexed arrays go to scratch. The old insertion sort had a
// dynamic v[j] -> localMem + dependent scratch round-trips at 32-block grid.
// A fully unrolled bitonic network keeps v[32] in VGPRs.
__global__ void k_sort_groups(int* __restrict__ groups)
{
    int gid = blockIdx.x * 256 + threadIdx.x;       // 2*N_ groups (gD then gS contiguous)
    if (gid >= 2 * N_) return;
    int* p = groups + (size_t)gid * K_;
    int v[32];
    #pragma unroll
    for (int i = 0; i < 32; ++i) v[i] = p[i];
    #pragma unroll
    for (int k = 2; k <= 32; k <<= 1) {
        #pragma unroll
        for (int j = k >> 1; j > 0; j >>= 1) {
            #pragma unroll
            for (int i = 0; i < 32; ++i) {
                int l = i ^ j;
                if (l > i) {
                    int a = v[i], b = v[l];
                    bool sw = ((i & k) == 0) ? (a > b) : (a < b);
                    v[i] = sw ? b : a;
                    v[l] = sw ? a : b;
                }
            }
        }
    }
    #pragma unroll
    for (int i = 0; i < 32; ++i) p[i] = v[i];
}

// ---------------- K6: dnd/sns edge columns + cosines ----------------
__global__ void k_dnd_sns(const int* __restrict__ ei, const int* __restrict__ gD,
                          const int* __restrict__ gS, float* __restrict__ out)
{
    size_t i = (size_t)blockIdx.x * 256 + threadIdx.x;  // E_*K_ threads
    int e = (int)(i >> 5);
    int j = (int)(i & 31);
    int s = ei[e];
    int d = ei[E_ + e];
    const float* vh = out + OFF_VHAT;
    float hx = vh[(size_t)e*3+0], hy = vh[(size_t)e*3+1], hz = vh[(size_t)e*3+2];

    int g1 = gD[(size_t)d * K_ + j];
    out[OFF_EDGES + EC_DND + i]           = (float)(N_ + e);
    out[OFF_EDGES + TE_COLS + EC_DND + i] = (float)(N_ + g1);
    out[OFF_CDD + i] = hx*vh[(size_t)g1*3+0] + hy*vh[(size_t)g1*3+1] + hz*vh[(size_t)g1*3+2];

    int g2 = gS[(size_t)s * K_ + j];
    out[OFF_EDGES + EC_SNS + i]           = (float)(N_ + e);
    out[OFF_EDGES + TE_COLS + EC_SNS + i] = (float)(N_ + g2);
    out[OFF_CSS + i] = hx*vh[(size_t)g2*3+0] + hy*vh[(size_t)g2*3+1] + hz*vh[(size_t)g2*3+2];
}

// ---------------- K7a: pre-convert w1/w2 to bf16 fragment-ready layouts -----
// w1f (A-frag for h^T GEMM1): [cb64][kblk2][L64][i8] = w1[kblk*32+(L>>4)*8+i][cb*16+(L&15)]
//   (k>=50 -> 0).  lane L holds row ff=cb*16+(L&15), cols k=(L>>4)*8+i of w1^T.
// w2f: [kblk32][cblk32][kg4][c16][i8] = w2[kblk*32+kg*8+i][cblk*16+c]  (unchanged)
__global__ void k_prep_w(const float* __restrict__ w1, const float* __restrict__ w2,
                         short* __restrict__ w1f, short* __restrict__ w2f)
{
    int idx = blockIdx.x * 256 + threadIdx.x;
    if (idx < 65536) {
        int i = idx & 7, L = (idx >> 3) & 63, kblk = (idx >> 9) & 1, cb = idx >> 10;
        int k = kblk*32 + (L >> 4)*8 + i, col = cb*16 + (L & 15);
        float v = (k < NG_) ? w1[(size_t)k * FF_ + col] : 0.0f;
        w1f[idx] = f2bf(v);
    } else {
        int j = idx - 65536;
        if (j < 524288) {
            int i = j & 7, cc = (j >> 3) & 15, kg = (j >> 7) & 3;
            int cblk = (j >> 9) & 31, kblk = j >> 14;
            int k = kblk*32 + kg*8 + i, col = cblk*16 + cc;
            w2f[j] = f2bf(w2[(size_t)k * D_ + col]);
        }
    }
}

// ---------------- K7b: fused edge MLP via bf16 MFMA ----------------
// Block: 512 threads = 8 waves, 64 edges. FF processed in 16 chunks of 64.
// GEMM1 is computed TRANSPOSED: D = mfma(w1^T-frag, rbf-frag) -> D[ff][e], so
// lane (reg r=0..3) holds 4 consecutive ff at one edge -> one aligned short4
// -> 2 conflict-free ds_write_b64 per thread per chunk (was 8 scalar b16 with
// 4-8-way bank conflicts).  GEMM2 (wave w owns output cols [w*64,w*64+64))
// and the LDS h layout are unchanged.
__global__ __launch_bounds__(512) void k_edge_fused(
    const short* __restrict__ w1f, const short* __restrict__ w2f,
    const float* __restrict__ b1, const float* __restrict__ b2,
    const float* __restrict__ te, float* __restrict__ out)
{
    __shared__ short s_rbf[4096];          // [(etile*2 + kblk)*64 + L]*8+i
    __shared__ short s_h[2][4096];         // frag-ready h chunk, double-buffered
    const int tid = threadIdx.x;
    const int e0  = blockIdx.x * 64;

    // ---- rbf into frag-ready LDS (one short8 per thread, linear) ----
    // same per-lane data serves as B-fragment (rbf^T: lane holds col e, rows k)
    {
        int f = tid;
        int lane = f & 63, kblk = (f >> 6) & 1, mf = f >> 7;
        int e_local = mf*16 + (lane & 15);
        int k0 = kblk*32 + (lane >> 4) * 8;
        float dist = out[OFF_DIST + e0 + e_local];
        short8 v;
        #pragma unroll
        for (int i = 0; i < 8; ++i) {
            int k = k0 + i;
            float val = 0.0f;
            if (k < NG_) { float dd = dist - (float)k * RBF_DELTA; val = __expf(RBF_COEFF*dd*dd); }
            v[i] = f2bf(val);
        }
        *(short8*)&s_rbf[f * 8] = v;
    }
    __syncthreads();

    const int w  = tid >> 6, L = tid & 63;
    const int kg = L >> 4, lc = L & 15;
    const int ft    = w >> 1;          // ff-tile within chunk (0..3)
    const int ebase = (w & 1) * 2;     // e-tiles ebase, ebase+1

    // GEMM1 B-frags (rbf) are chunk-independent: load once
    short8 br[2][2];                   // [j][kblk]
    #pragma unroll
    for (int j = 0; j < 2; ++j)
        #pragma unroll
        for (int kb = 0; kb < 2; ++kb)
            br[j][kb] = *(const short8*)&s_rbf[(((ebase + j)*2 + kb)*64 + L) * 8];

    // scatter address pieces (chunk-independent)
    const int ffc0 = ft*16 + kg*4;                 // ff-in-chunk of reg r=0
    const int skb  = ffc0 >> 5;
    const int sisl = ffc0 & 7;                     // 0 or 4 -> 8B-aligned
    const int sl2  = ((ffc0 & 31) >> 3)*16 + lc;   // consumer lane

    const f32x4 Z = {0.0f, 0.0f, 0.0f, 0.0f};
    f32x4 acc[4][4];
    #pragma unroll
    for (int m = 0; m < 4; ++m)
        #pragma unroll
        for (int n = 0; n < 4; ++n) acc[m][n] = Z;

    for (int c = 0; c < 16; ++c) {
        // ---- GEMM1 (transposed): h^T chunk frags, A = w1^T, B = rbf ----
        int cb = c*4 + ft;                         // global ff-tile (0..63)
        short8 aw0 = *(const short8*)&w1f[((cb*2 + 0)*64 + L) * 8];
        short8 aw1 = *(const short8*)&w1f[((cb*2 + 1)*64 + L) * 8];
        f32x4 d1[2];
        #pragma unroll
        for (int j = 0; j < 2; ++j) {
            f32x4 t = MFMA(aw0, br[j][0], Z);
            d1[j] = MFMA(aw1, br[j][1], t);        // D[ff][e]: row ff=(L>>4)*4+r, col e=L&15
        }
        // ---- bias + silu -> frag-ready LDS, one ds_write_b64 per task ----
        short* hb = s_h[c & 1];
        f32x4 b4 = *(const f32x4*)&b1[c*64 + ffc0];
        #pragma unroll
        for (int j = 0; j < 2; ++j) {
            s16x4 pk;
            #pragma unroll
            for (int r = 0; r < 4; ++r) {
                float x = d1[j][r] + b4[r];
                float sv = x * __fdividef(1.0f, 1.0f + __expf(-x));
                pk[r] = f2bf(sv);
            }
            *(s16x4*)&hb[((((ebase + j)*2 + skb)*64 + sl2) * 8) + sisl] = pk;
        }
        __syncthreads();
        // ---- GEMM2 over this chunk: wave w -> cols [w*64, w*64+64) ----
        const short* hr = s_h[c & 1];
        short8 a2[4][2], bw[4][2];
        #pragma unroll
        for (int kb = 0; kb < 2; ++kb) {
            #pragma unroll
            for (int nfo = 0; nfo < 4; ++nfo)
                bw[nfo][kb] = *(const short8*)&w2f[(((c*2 + kb)*32 + (w*4 + nfo))*64 + L) * 8];
            #pragma unroll
            for (int m = 0; m < 4; ++m)
                a2[m][kb] = *(const short8*)&hr[((m*2 + kb)*64 + L) * 8];
        }
        #pragma unroll
        for (int m = 0; m < 4; ++m)
            #pragma unroll
            for (int nfo = 0; nfo < 4; ++nfo) {
                acc[m][nfo] = MFMA(a2[m][0], bw[nfo][0], acc[m][nfo]);
                acc[m][nfo] = MFMA(a2[m][1], bw[nfo][1], acc[m][nfo]);
            }
    }

    // ---- epilogue: tokens rows N_+e ----
    float bb[4];
    #pragma unroll
    for (int nfo = 0; nfo < 4; ++nfo) {
        int col = w*64 + nfo*16 + lc;
        bb[nfo] = b2[col] + te[D_ + col];          // b2 + type_embedding[1]
    }
    #pragma unroll
    for (int m = 0; m < 4; ++m) {
        int row0 = e0 + m*16 + kg*4;
        #pragma unroll
        for (int nfo = 0; nfo < 4; ++nfo) {
            int col = w*64 + nfo*16 + lc;
            #pragma unroll
            for (int r = 0; r < 4; ++r)
                out[OFF_TOK + (size_t)(N_ + row0 + r) * D_ + col] =
                    INV_SQRT2 * (acc[m][nfo][r] + bb[nfo]);
        }
    }
}

// ---------------- launch ----------------
extern "C" void kernel_launch(void* const* d_in, const int* in_sizes, int n_in,
                              void* d_out, int out_size, void* d_ws, size_t ws_size,
                              hipStream_t stream)
{
    const float* pos = (const float*)d_in[0];
    const int*   an  = (const int*)d_in[2];
    const int*   ei  = (const int*)d_in[3];
    const float* emb = (const float*)d_in[4];
    const float* te  = (const float*)d_in[5];
    const float* w1  = (const float*)d_in[6];
    const float* b1  = (const float*)d_in[7];
    const float* w2  = (const float*)d_in[8];
    const float* b2  = (const float*)d_in[9];
    float* out = (float*)d_out;

    // workspace: cntD[N] cntS[N] gD[E] gS[E] | w1f | w2f   (~2.3 MB)
    int* cntD = (int*)d_ws;
    int* cntS = cntD + N_;
    int* gD   = cntS + N_;
    int* gS   = gD + E_;
    short* w1f = (short*)((char*)d_ws + 1081344);   // 16B-aligned
    short* w2f = w1f + 65536;

    hipMemsetAsync(cntD, 0, 2 * N_ * sizeof(int), stream);

    k_prep_w      <<<2304, 256, 0, stream>>>(w1, w2, w1f, w2f);
    k_node_tokens <<<2048, 256, 0, stream>>>(an, emb, te, out);
    k_edge_geom   <<<E_/256, 256, 0, stream>>>(pos, ei, out, cntD, cntS, gD, gS);
    k_all_pairs   <<<262144/256, 256, 0, stream>>>(pos, out);
    k_sort_groups <<<(2*N_)/256, 256, 0, stream>>>(gD);
    k_dnd_sns     <<<(E_*K_)/256, 256, 0, stream>>>(ei, gD, gS, out);
    k_edge_fused  <<<E_/64, 512, 0, stream>>>(w1f, w2f, b1, b2, te, out);
}